// Round 8
// baseline (20.875 us; speedup 1.0000x reference)
//
#include <hip/hip_runtime.h>
#include <math.h>

// ---------------------------------------------------------------------------
// QuantumResidualRegressor R8: wave-paired split for 2x occupancy.
//   Waves 2k/2k+1 cooperate on the same 64 samples: each wave handles half
//   the features (L1), half the h-outputs, half the qubits, half the head.
//   'subw' is wave-uniform -> weight reads stay s_load, split branches are
//   scalar branches, no dynamic register indexing. Exchanges via small
//   lane-contiguous LDS buffers (conflict-free), 6 barriers total.
//   4096 waves = 4 waves/SIMD (vs 2), per-wave work and s_load round trips
//   halved. Circuit stays X-basis collapsed (validated R4-R7).
// ---------------------------------------------------------------------------

typedef float f32x2 __attribute__((ext_vector_type(2)));

// X-basis CNOT-ring permutation (one layer) on 6-bit indices.
__host__ __device__ constexpr int Lmap(int j) {
    int b5=(j>>5)&1, b4=(j>>4)&1, b3=(j>>3)&1, b2=(j>>2)&1, b1=(j>>1)&1, b0=j&1;
    int o5=b5^b4, o4=b4^b3, o3=b3^b2, o2=b2^b1, o1=b1^b0, o0=b0^b5^b4;
    return (o5<<5)|(o4<<4)|(o3<<3)|(o2<<2)|(o1<<1)|o0;
}
__host__ __device__ constexpr int Linv(int j) {
    int o5=(j>>5)&1, o4=(j>>4)&1, o3=(j>>3)&1, o2=(j>>2)&1, o1=(j>>1)&1, o0=j&1;
    int b4 = o5^o4^o3^o2^o1^o0;
    int b5 = b4^o5;
    int b3 = b4^o4;
    int b2 = b3^o3;
    int b1 = b2^o2;
    int b0 = b1^o1;
    return (b5<<5)|(b4<<4)|(b3<<3)|(b2<<2)|(b1<<1)|b0;
}
__host__ __device__ constexpr int MPc(int q) {   // m'_q = L^{-3} (bit 5-q)
    int m = 1 << (5 - q);
    m = Linv(m); m = Linv(m); m = Linv(m);
    return m;
}
__host__ __device__ constexpr int popc6(int m) {
    int c = 0;
    for (int p = 0; p < 6; ++p) c += (m >> p) & 1;
    return c;
}

__device__ __forceinline__ float fast_rcp(float x) { return __builtin_amdgcn_rcpf(x); }
__device__ __forceinline__ f32x2 bc2(float s) { return (f32x2){s, s}; }

__device__ __forceinline__ float fast_tanh(float x) {
    float e = __expf(2.0f * x);
    return fmaf(-2.0f, fast_rcp(1.0f + e), 1.0f);
}
__device__ __forceinline__ float fast_gelu(float x) {
    float x2 = x * x;
    float inner = x * fmaf(x2, 0.0356774081f, 0.7978845608f);
    float t = fast_tanh(inner);
    return 0.5f * x * (1.0f + t);
}
__device__ __forceinline__ f32x2 fast_gelu2(f32x2 x) {
    return (f32x2){ fast_gelu(x.x), fast_gelu(x.y) };
}

// z_q = c_q * sum_r K[(Q%3)*8+r] * prod_{free bits p} u2[p][bit_p(r)]
// K holds only this wave's 24 entries (q-group subw*3..subw*3+2).
template<int Q>
__device__ __forceinline__ float zq_eval(const float (&u2)[6][2], const float (&u01)[6],
                                         const float (&K)[24]) {
    constexpr int mp = MPc(Q);
    constexpr int F  = (~mp) & 63;
    constexpr int nf = 6 - popc6(mp);
    float cq = 1.0f;
    #pragma unroll
    for (int p = 0; p < 6; ++p) if ((mp >> p) & 1) cq *= u01[p];
    float acc = 0.0f;
    #pragma unroll
    for (int r = 0; r < (1 << nf); ++r) {
        float t = K[(Q % 3) * 8 + r];
        int k = nf;
        #pragma unroll
        for (int p = 5; p >= 0; --p) if ((F >> p) & 1) { --k; t *= u2[p][(r >> k) & 1]; }
        acc += t;
    }
    return acc * cq;
}

__global__ __launch_bounds__(256) __attribute__((amdgpu_waves_per_eu(4, 4)))
void qrr_kernel(const float* __restrict__ features,
                const float* __restrict__ baseline,
                const float* __restrict__ enc_w1,
                const float* __restrict__ enc_b1,
                const float* __restrict__ enc_w2,
                const float* __restrict__ enc_b2,
                const float* __restrict__ q_weights,
                const float* __restrict__ head_w1,
                const float* __restrict__ head_b1,
                const float* __restrict__ head_w2,
                const float* __restrict__ head_b2,
                float* __restrict__ out,
                int n)   // assumes n % 128 == 0
{
    __shared__ float phi[64];
    __shared__ __align__(16) float KTs[48];
    // exchange buffers: [pair][srcwave][slot][lane] -> lane-contiguous, no conflicts
    __shared__ __align__(16) f32x2 XH[2][2][4][64];   // h partials (4 f32x2 = o-octet)
    __shared__ float XP[2][2][3][64];                 // L2 partials (3 q)
    __shared__ float XU[2][2][9][64];                 // u triplets (3q x {u20,u21,u01})
    __shared__ float XZ[2][2][3][64];                 // z values
    __shared__ float XR[2][64];                       // head partial dot

    const int tid  = threadIdx.x;
    const int lane = tid & 63;
    const int subw = (tid >> 6) & 1;   // which half of the pair (wave-uniform)
    const int P    = tid >> 7;         // pair index within block (wave-uniform)

    // ---- stage A: uniform phases Phi_j (threads 0..63) ----
    if (tid < 64) {
        int jl = tid;
        float acc = 0.0f;
        for (int l = 0; l < 3; ++l) {
            for (int q = 0; q < 6; ++q)
                acc += q_weights[l * 6 + q] * (((jl >> (5 - q)) & 1) ? 0.5f : -0.5f);
            jl = Lmap(jl);
        }
        phi[tid] = acc;
    }
    __syncthreads();                                   // barrier 1

    // ---- stage B: K~[q][r] (threads 0..47); barrier folded into X1's ----
    if (tid < 48) {
        const int q = tid >> 3, r = tid & 7;
        const int mp = Linv(Linv(Linv(1 << (5 - q))));
        const int F  = (~mp) & 63;
        const int nf = __popc(F), pm = 6 - nf;
        float kv = 0.0f;
        if (r < (1 << nf)) {
            int jb = 0, k = nf;
            for (int p = 5; p >= 0; --p)
                if ((F >> p) & 1) { --k; if ((r >> k) & 1) jb |= 1 << p; }
            float s = 0.0f;
            for (int e = 0; e < (1 << pm); ++e) {
                int je = 0, kk = pm;
                for (int p = 5; p >= 0; --p)
                    if ((mp >> p) & 1) { --kk; if ((e >> kk) & 1) je |= 1 << p; }
                const int j0 = jb | je;
                s += __cosf(phi[j0 ^ mp] - phi[j0]);
            }
            kv = s * (1.0f / 64.0f);
        }
        KTs[tid] = kv;
    }

    const int s = blockIdx.x * 128 + P * 64 + lane;

    // ---- features: this wave's 16 of 32 ----
    float f[16];
    {
        const float4* fp = reinterpret_cast<const float4*>(
            features + (size_t)s * 32 + subw * 16);
        #pragma unroll
        for (int k = 0; k < 4; ++k) {
            float4 v = fp[k];
            f[4*k+0] = v.x; f[4*k+1] = v.y; f[4*k+2] = v.z; f[4*k+3] = v.w;
        }
    }
    float base = 0.0f;
    if (subw == 0) base = baseline[s];

    // ---- L1 partials over my 16 features, ALL 16 outputs (f32x2 o-pairs) ----
    const float* w1p = enc_w1 + subw * 256;            // rows subw*16..subw*16+15
    f32x2 part2[8];
    #pragma unroll
    for (int o = 0; o < 8; ++o) part2[o] = bc2(0.0f);
    #pragma unroll
    for (int i = 0; i < 16; ++i) {
        const f32x2 fv = bc2(f[i]);
        const f32x2* w = reinterpret_cast<const f32x2*>(w1p + i * 16);
        #pragma unroll
        for (int o = 0; o < 8; ++o)
            part2[o] = __builtin_elementwise_fma(fv, w[o], part2[o]);
    }
    // write the half the OTHER wave owns
    if (subw == 0) {
        #pragma unroll
        for (int k = 0; k < 4; ++k) XH[P][0][k][lane] = part2[4 + k];  // o8..15
    } else {
        #pragma unroll
        for (int k = 0; k < 4; ++k) XH[P][1][k][lane] = part2[k];      // o0..7
    }
    __syncthreads();                                   // barrier 2 (also KTs ready)

    // ---- combine + bias + GELU on my 8 outputs ----
    f32x2 g2[4];
    {
        const f32x2* b1p = reinterpret_cast<const f32x2*>(enc_b1 + subw * 8);
        if (subw == 0) {
            #pragma unroll
            for (int k = 0; k < 4; ++k)
                g2[k] = fast_gelu2(part2[k] + XH[P][1][k][lane] + b1p[k]);
        } else {
            #pragma unroll
            for (int k = 0; k < 4; ++k)
                g2[k] = fast_gelu2(part2[4 + k] + XH[P][0][k][lane] + b1p[k]);
        }
    }
    float g[8];
    #pragma unroll
    for (int k = 0; k < 4; ++k) { g[2*k] = g2[k].x; g[2*k+1] = g2[k].y; }

    // ---- L2 partials over my 8 h-elems, all 6 q ----
    const float* w2p = enc_w2 + (subw * 8) * 6;        // rows subw*8..subw*8+7
    float pq[6] = {0,0,0,0,0,0};
    #pragma unroll
    for (int k = 0; k < 8; ++k) {
        #pragma unroll
        for (int q = 0; q < 6; ++q)
            pq[q] = fmaf(g[k], w2p[k * 6 + q], pq[q]);
    }
    if (subw == 0) {
        #pragma unroll
        for (int j = 0; j < 3; ++j) XP[P][0][j][lane] = pq[3 + j];
    } else {
        #pragma unroll
        for (int j = 0; j < 3; ++j) XP[P][1][j][lane] = pq[j];
    }
    __syncthreads();                                   // barrier 3

    // ---- finish my 3 qubits: a -> tanh -> sin/cos -> u ----
    float u20[3], u21[3], u01m[3];
    {
        #pragma unroll
        for (int j = 0; j < 3; ++j) {
            float a;
            if (subw == 0) a = pq[j]     + XP[P][1][j][lane] + enc_b2[j];
            else           a = pq[3 + j] + XP[P][0][j][lane] + enc_b2[3 + j];
            const float w = fast_tanh(a);
            const float sn = __sinf(w), cs = __cosf(w);
            u20[j] = 1.0f + sn;
            u21[j] = 1.0f - sn;
            u01m[j] = cs;
        }
    }
    #pragma unroll
    for (int j = 0; j < 3; ++j) {
        XU[P][subw][j][lane]     = u20[j];
        XU[P][subw][3 + j][lane] = u21[j];
        XU[P][subw][6 + j][lane] = u01m[j];
    }
    __syncthreads();                                   // barrier 4

    // ---- assemble full u arrays (bit position p = 5 - q) ----
    float u2[6][2], u01[6];
    if (subw == 0) {
        // mine q=0,1,2 -> p=5,4,3 ; other's q=3,4,5 -> p=2,1,0
        u2[5][0]=u20[0]; u2[5][1]=u21[0]; u01[5]=u01m[0];
        u2[4][0]=u20[1]; u2[4][1]=u21[1]; u01[4]=u01m[1];
        u2[3][0]=u20[2]; u2[3][1]=u21[2]; u01[3]=u01m[2];
        u2[2][0]=XU[P][1][0][lane]; u2[2][1]=XU[P][1][3][lane]; u01[2]=XU[P][1][6][lane];
        u2[1][0]=XU[P][1][1][lane]; u2[1][1]=XU[P][1][4][lane]; u01[1]=XU[P][1][7][lane];
        u2[0][0]=XU[P][1][2][lane]; u2[0][1]=XU[P][1][5][lane]; u01[0]=XU[P][1][8][lane];
    } else {
        // mine q=3,4,5 -> p=2,1,0 ; other's q=0,1,2 -> p=5,4,3
        u2[2][0]=u20[0]; u2[2][1]=u21[0]; u01[2]=u01m[0];
        u2[1][0]=u20[1]; u2[1][1]=u21[1]; u01[1]=u01m[1];
        u2[0][0]=u20[2]; u2[0][1]=u21[2]; u01[0]=u01m[2];
        u2[5][0]=XU[P][0][0][lane]; u2[5][1]=XU[P][0][3][lane]; u01[5]=XU[P][0][6][lane];
        u2[4][0]=XU[P][0][1][lane]; u2[4][1]=XU[P][0][4][lane]; u01[4]=XU[P][0][7][lane];
        u2[3][0]=XU[P][0][2][lane]; u2[3][1]=XU[P][0][5][lane]; u01[3]=XU[P][0][8][lane];
    }

    // ---- my half of K~ into registers (24 floats, 6x b128) ----
    float K[24];
    {
        const float4* kp = reinterpret_cast<const float4*>(&KTs[subw * 24]);
        #pragma unroll
        for (int i = 0; i < 6; ++i) {
            float4 v = kp[i];
            K[4*i+0] = v.x; K[4*i+1] = v.y; K[4*i+2] = v.z; K[4*i+3] = v.w;
        }
    }

    // ---- my 3 expvals ----
    float zm[3];
    if (subw == 0) {
        zm[0] = zq_eval<0>(u2, u01, K);
        zm[1] = zq_eval<1>(u2, u01, K);
        zm[2] = zq_eval<2>(u2, u01, K);
    } else {
        zm[0] = zq_eval<3>(u2, u01, K);
        zm[1] = zq_eval<4>(u2, u01, K);
        zm[2] = zq_eval<5>(u2, u01, K);
    }
    #pragma unroll
    for (int j = 0; j < 3; ++j) XZ[P][subw][j][lane] = zm[j];
    __syncthreads();                                   // barrier 5

    float z[6];
    if (subw == 0) {
        z[0]=zm[0]; z[1]=zm[1]; z[2]=zm[2];
        z[3]=XZ[P][1][0][lane]; z[4]=XZ[P][1][1][lane]; z[5]=XZ[P][1][2][lane];
    } else {
        z[3]=zm[0]; z[4]=zm[1]; z[5]=zm[2];
        z[0]=XZ[P][0][0][lane]; z[1]=XZ[P][0][1][lane]; z[2]=XZ[P][0][2][lane];
    }

    // ---- head: my 8 of 16 hidden units ----
    const float* hw1p = head_w1 + subw * 8;
    const float* hb1p = head_b1 + subw * 8;
    const float* hw2p = head_w2 + subw * 8;
    float hh[8];
    #pragma unroll
    for (int k = 0; k < 8; ++k) hh[k] = hb1p[k];
    #pragma unroll
    for (int i = 0; i < 6; ++i) {
        const float zi = z[i];
        #pragma unroll
        for (int k = 0; k < 8; ++k)
            hh[k] = fmaf(zi, hw1p[i * 16 + k], hh[k]);
    }
    float rp = 0.0f;
    #pragma unroll
    for (int k = 0; k < 8; ++k)
        rp = fmaf(fast_gelu(hh[k]), hw2p[k], rp);

    if (subw == 1) XR[P][lane] = rp;
    __syncthreads();                                   // barrier 6
    if (subw == 0)
        out[s] = base + rp + XR[P][lane] + head_b2[0];
}

extern "C" void kernel_launch(void* const* d_in, const int* in_sizes, int n_in,
                              void* d_out, int out_size, void* d_ws, size_t ws_size,
                              hipStream_t stream) {
    const float* features = (const float*)d_in[0];
    const float* baseline = (const float*)d_in[1];
    const float* enc_w1   = (const float*)d_in[2];
    const float* enc_b1   = (const float*)d_in[3];
    const float* enc_w2   = (const float*)d_in[4];
    const float* enc_b2   = (const float*)d_in[5];
    const float* q_weights= (const float*)d_in[6];
    const float* head_w1  = (const float*)d_in[7];
    const float* head_b1  = (const float*)d_in[8];
    const float* head_w2  = (const float*)d_in[9];
    const float* head_b2  = (const float*)d_in[10];
    float* out = (float*)d_out;

    const int n = in_sizes[0] / 32;          // B, multiple of 128
    const int grid = n / 128;                // 128 samples per block
    qrr_kernel<<<grid, 256, 0, stream>>>(features, baseline,
                                         enc_w1, enc_b1, enc_w2, enc_b2,
                                         q_weights,
                                         head_w1, head_b1, head_w2, head_b2,
                                         out, n);
}

// Round 9
// 15.889 us; speedup vs baseline: 1.3138x; 1.3138x over previous
//
#include <hip/hip_runtime.h>
#include <math.h>

// ---------------------------------------------------------------------------
// QuantumResidualRegressor R9: R6 structure + front-loaded global loads.
//   Features/baseline loads issued BEFORE the phi/K prologue so their ~900cy
//   HBM latency hides under the prologue compute + barriers. Everything else
//   identical to R6 (best so far: X-basis collapsed circuit, s_load weights,
//   K~ in registers, rcp/sin identities, waves_per_eu(2,2)).
// ---------------------------------------------------------------------------

typedef float f32x2 __attribute__((ext_vector_type(2)));

// X-basis CNOT-ring permutation (one layer) on 6-bit indices.
__host__ __device__ constexpr int Lmap(int j) {
    int b5=(j>>5)&1, b4=(j>>4)&1, b3=(j>>3)&1, b2=(j>>2)&1, b1=(j>>1)&1, b0=j&1;
    int o5=b5^b4, o4=b4^b3, o3=b3^b2, o2=b2^b1, o1=b1^b0, o0=b0^b5^b4;
    return (o5<<5)|(o4<<4)|(o3<<3)|(o2<<2)|(o1<<1)|o0;
}
__host__ __device__ constexpr int Linv(int j) {
    int o5=(j>>5)&1, o4=(j>>4)&1, o3=(j>>3)&1, o2=(j>>2)&1, o1=(j>>1)&1, o0=j&1;
    int b4 = o5^o4^o3^o2^o1^o0;
    int b5 = b4^o5;
    int b3 = b4^o4;
    int b2 = b3^o3;
    int b1 = b2^o2;
    int b0 = b1^o1;
    return (b5<<5)|(b4<<4)|(b3<<3)|(b2<<2)|(b1<<1)|b0;
}
__host__ __device__ constexpr int MPc(int q) {   // m'_q = L^{-3} (bit 5-q)
    int m = 1 << (5 - q);
    m = Linv(m); m = Linv(m); m = Linv(m);
    return m;
}
__host__ __device__ constexpr int popc6(int m) {
    int c = 0;
    for (int p = 0; p < 6; ++p) c += (m >> p) & 1;
    return c;
}

__device__ __forceinline__ float fast_rcp(float x) { return __builtin_amdgcn_rcpf(x); }

__device__ __forceinline__ float fast_tanh(float x) {
    float e = __expf(2.0f * x);
    return fmaf(-2.0f, fast_rcp(1.0f + e), 1.0f);
}
__device__ __forceinline__ float fast_gelu(float x) {
    float x2 = x * x;
    float inner = x * fmaf(x2, 0.0356774081f, 0.7978845608f);
    float t = fast_tanh(inner);
    return 0.5f * x * (1.0f + t);
}

// z_q = c_q * sum_r K[q*8+r] * prod_{free bits p} u2[p][bit_p(r)]
template<int Q>
__device__ __forceinline__ float zq_eval(const float (&u2)[6][2], const float (&u01)[6],
                                         const float (&K)[48]) {
    constexpr int mp = MPc(Q);
    constexpr int F  = (~mp) & 63;
    constexpr int nf = 6 - popc6(mp);
    float cq = 1.0f;
    #pragma unroll
    for (int p = 0; p < 6; ++p) if ((mp >> p) & 1) cq *= u01[p];
    float acc = 0.0f;
    #pragma unroll
    for (int r = 0; r < (1 << nf); ++r) {
        float t = K[Q * 8 + r];
        int k = nf;
        #pragma unroll
        for (int p = 5; p >= 0; --p) if ((F >> p) & 1) { --k; t *= u2[p][(r >> k) & 1]; }
        acc += t;
    }
    return acc * cq;
}

__global__ __launch_bounds__(256) __attribute__((amdgpu_waves_per_eu(2, 2)))
void qrr_kernel(const float* __restrict__ features,
                const float* __restrict__ baseline,
                const float* __restrict__ enc_w1,
                const float* __restrict__ enc_b1,
                const float* __restrict__ enc_w2,
                const float* __restrict__ enc_b2,
                const float* __restrict__ q_weights,
                const float* __restrict__ head_w1,
                const float* __restrict__ head_b1,
                const float* __restrict__ head_w2,
                const float* __restrict__ head_b2,
                float* __restrict__ out,
                int n)
{
    __shared__ float phi[64];
    __shared__ __align__(16) float KTs[48];
    const int tid = threadIdx.x;

    // ---- front-load the per-sample global reads (hide HBM latency under
    //      the prologue compute + barriers) ----
    const int gid = blockIdx.x * 256 + tid;
    const int b = (gid < n) ? gid : (n - 1);      // exact grid in practice
    float4 fv4[8];
    {
        const float4* fp = reinterpret_cast<const float4*>(features + (size_t)b * 32);
        #pragma unroll
        for (int k = 0; k < 8; ++k) fv4[k] = fp[k];
    }
    const float base = baseline[b];

    // ---- stage A: uniform phases Phi_j (threads 0..63) ----
    if (tid < 64) {
        int jl = tid;
        float acc = 0.0f;
        for (int l = 0; l < 3; ++l) {
            for (int q = 0; q < 6; ++q)
                acc += q_weights[l * 6 + q] * (((jl >> (5 - q)) & 1) ? 0.5f : -0.5f);
            jl = Lmap(jl);
        }
        phi[tid] = acc;
    }
    __syncthreads();

    // ---- stage B: K~[q][r] (threads 0..47) ----
    if (tid < 48) {
        const int q = tid >> 3, r = tid & 7;
        const int mp = Linv(Linv(Linv(1 << (5 - q))));
        const int F  = (~mp) & 63;
        const int nf = __popc(F), pm = 6 - nf;
        float kv = 0.0f;
        if (r < (1 << nf)) {
            int jb = 0, k = nf;
            for (int p = 5; p >= 0; --p)
                if ((F >> p) & 1) { --k; if ((r >> k) & 1) jb |= 1 << p; }
            float s = 0.0f;
            for (int e = 0; e < (1 << pm); ++e) {
                int je = 0, kk = pm;
                for (int p = 5; p >= 0; --p)
                    if ((mp >> p) & 1) { --kk; if ((e >> kk) & 1) je |= 1 << p; }
                const int j0 = jb | je;
                s += __cosf(phi[j0 ^ mp] - phi[j0]);
            }
            kv = s * (1.0f / 64.0f);
        }
        KTs[tid] = kv;
    }
    __syncthreads();

    // ---- unpack features (already in VGPRs) ----
    float f[32];
    #pragma unroll
    for (int k = 0; k < 8; ++k) {
        f[4*k+0] = fv4[k].x; f[4*k+1] = fv4[k].y;
        f[4*k+2] = fv4[k].z; f[4*k+3] = fv4[k].w;
    }

    // ---- encoder L1: [32]->[16] GELU; weights via uniform s_load ----
    f32x2 h2[8];
    {
        const f32x2* bb = reinterpret_cast<const f32x2*>(enc_b1);
        #pragma unroll
        for (int o = 0; o < 8; ++o) h2[o] = bb[o];
    }
    #pragma unroll
    for (int i = 0; i < 32; ++i) {
        const f32x2 fv = {f[i], f[i]};
        const f32x2* w = reinterpret_cast<const f32x2*>(enc_w1 + i * 16);
        #pragma unroll
        for (int o = 0; o < 8; ++o)
            h2[o] = __builtin_elementwise_fma(fv, w[o], h2[o]);
    }
    float h[16];
    #pragma unroll
    for (int o = 0; o < 8; ++o) {
        h[2*o]   = fast_gelu(h2[o].x);
        h[2*o+1] = fast_gelu(h2[o].y);
    }

    // ---- encoder L2: [16]->[6] tanh(a)=w -> u2 = 1±sin(w), u01 = cos(w) ----
    float u2[6][2], u01[6];
    #pragma unroll
    for (int q = 0; q < 6; ++q) {
        float a = enc_b2[q];
        #pragma unroll
        for (int i = 0; i < 16; ++i)
            a = fmaf(h[i], enc_w2[i * 6 + q], a);
        const float w = fast_tanh(a);
        float sn, cs;
        __sincosf(w, &sn, &cs);
        const int p = 5 - q;                  // bit position of qubit q
        u2[p][0] = 1.0f + sn;
        u2[p][1] = 1.0f - sn;
        u01[p]   = cs;
    }

    // ---- pull K~ into registers (12x ds_read_b128, constant offsets) ----
    float K[48];
    {
        const float4* kp = reinterpret_cast<const float4*>(KTs);
        #pragma unroll
        for (int i = 0; i < 12; ++i) {
            float4 v = kp[i];
            K[4*i+0] = v.x; K[4*i+1] = v.y; K[4*i+2] = v.z; K[4*i+3] = v.w;
        }
    }

    // ---- expvals via factored quadratic forms (K in registers) ----
    float z[6];
    z[0] = zq_eval<0>(u2, u01, K);
    z[1] = zq_eval<1>(u2, u01, K);
    z[2] = zq_eval<2>(u2, u01, K);
    z[3] = zq_eval<3>(u2, u01, K);
    z[4] = zq_eval<4>(u2, u01, K);
    z[5] = zq_eval<5>(u2, u01, K);

    // ---- head: [6]->[16] GELU ->[1] ----
    f32x2 hh2[8];
    {
        const f32x2* bb = reinterpret_cast<const f32x2*>(head_b1);
        #pragma unroll
        for (int o = 0; o < 8; ++o) hh2[o] = bb[o];
    }
    #pragma unroll
    for (int i = 0; i < 6; ++i) {
        const f32x2 zv = {z[i], z[i]};
        const f32x2* w = reinterpret_cast<const f32x2*>(head_w1 + i * 16);
        #pragma unroll
        for (int o = 0; o < 8; ++o)
            hh2[o] = __builtin_elementwise_fma(zv, w[o], hh2[o]);
    }
    float r = head_b2[0];
    #pragma unroll
    for (int o = 0; o < 8; ++o) {
        r = fmaf(fast_gelu(hh2[o].x), head_w2[2*o],     r);
        r = fmaf(fast_gelu(hh2[o].y), head_w2[2*o + 1], r);
    }

    out[b] = base + r;
}

extern "C" void kernel_launch(void* const* d_in, const int* in_sizes, int n_in,
                              void* d_out, int out_size, void* d_ws, size_t ws_size,
                              hipStream_t stream) {
    const float* features = (const float*)d_in[0];
    const float* baseline = (const float*)d_in[1];
    const float* enc_w1   = (const float*)d_in[2];
    const float* enc_b1   = (const float*)d_in[3];
    const float* enc_w2   = (const float*)d_in[4];
    const float* enc_b2   = (const float*)d_in[5];
    const float* q_weights= (const float*)d_in[6];
    const float* head_w1  = (const float*)d_in[7];
    const float* head_b1  = (const float*)d_in[8];
    const float* head_w2  = (const float*)d_in[9];
    const float* head_b2  = (const float*)d_in[10];
    float* out = (float*)d_out;

    const int n = in_sizes[0] / 32;          // B
    const int block = 256;
    const int grid = (n + block - 1) / block;
    qrr_kernel<<<grid, block, 0, stream>>>(features, baseline,
                                           enc_w1, enc_b1, enc_w2, enc_b2,
                                           q_weights,
                                           head_w1, head_b1, head_w2, head_b2,
                                           out, n);
}